// Round 5
// baseline (201.136 us; speedup 1.0000x reference)
//
#include <hip/hip_runtime.h>

#define NH 8
#define HD 32
#define NL 4
#define NP 4
#define DM 256
#define LEN_IN_C 13294
#define LQ_C 13294
#define B_C 2
#define M_TOTAL (B_C * LQ_C)           // 26588
#define MT_TILES 1662                  // ceil(26588/16)
#define RT32_TILES 831                 // ceil(26588/32)
#define GQ 32                          // queries per sampler block
#define QBLKS 831                      // ceil(26588/32)

typedef __attribute__((ext_vector_type(8))) short short8;
typedef __attribute__((ext_vector_type(4))) float floatx4;

__device__ __forceinline__ unsigned short f2bf(float x) {
    union { float f; unsigned int u; } a; a.f = x;
    unsigned int r = (a.u + 0x7FFFu + ((a.u >> 16) & 1u)) >> 16;
    return (unsigned short)r;
}
__device__ __forceinline__ unsigned short f2h(float x) {
    unsigned int r;
    asm("v_cvt_f16_f32 %0, %1" : "=v"(r) : "v"(x));
    return (unsigned short)r;
}
__device__ __forceinline__ unsigned int cvtpk_bf16(float lo, float hi) {
    unsigned int r;
    asm("v_cvt_pk_bf16_f32 %0, %1, %2" : "=v"(r) : "v"(lo), "v"(hi));
    return r;
}

// acc += f16(lo/hi half of v) * w   — one VALU op, f32 accumulate.
#define FMAMIX_LO(acc, v, w) \
    asm("v_fma_mix_f32 %0, %1, %2, %0 op_sel_hi:[1,0,0]" : "+v"(acc) : "v"(v), "v"(w))
#define FMAMIX_HI(acc, v, w) \
    asm("v_fma_mix_f32 %0, %1, %2, %0 op_sel:[1,0,0] op_sel_hi:[1,0,0]" : "+v"(acc) : "v"(v), "v"(w))

// ---------------------------------------------------------------------------
// Weight conversions + bias fuse + pad/tail zeroing in ONE kernel.
// ---------------------------------------------------------------------------
__device__ __forceinline__ void conv_b_body(const float* __restrict__ W,
                                            unsigned short* __restrict__ Bsw,
                                            int Nsrc, int NTsrc, int NTtotal, int ntOff,
                                            int vblk) {
    const int u = vblk * 256 + threadIdx.x;
    const int lane = u & 63;
    const int unit = u >> 6;
    const int ntl = unit % NTsrc;
    const int kc = unit / NTsrc;
    const int n = ntl * 16 + (lane & 15);
    const int k0 = kc * 32 + (lane >> 4) * 8;
    short8 v;
#pragma unroll
    for (int j = 0; j < 8; ++j)
        v[j] = (short)f2bf(W[(size_t)(k0 + j) * Nsrc + n]);
    ((short8*)Bsw)[(size_t)(kc * NTtotal + ntOff + ntl) * 64 + lane] = v;
}

__global__ __launch_bounds__(256) void conv_weights_kernel(const float* __restrict__ Wv,
                                                           const float* __restrict__ Woff,
                                                           const float* __restrict__ Wattn,
                                                           const float* __restrict__ Wout,
                                                           const float* __restrict__ boff,
                                                           const float* __restrict__ battn,
                                                           unsigned short* __restrict__ BswV,
                                                           unsigned short* __restrict__ BswOA,
                                                           unsigned short* __restrict__ BswO,
                                                           float* __restrict__ fbias,
                                                           unsigned short* __restrict__ value,
                                                           unsigned short* __restrict__ AccSw) {
    const int blk = blockIdx.x;
    if (blk < 32)        conv_b_body(Wv,    BswV,  256, 16, 16, 0,  blk);
    else if (blk < 64)   conv_b_body(Woff,  BswOA, 256, 16, 24, 0,  blk - 32);
    else if (blk < 80)   conv_b_body(Wattn, BswOA, 128,  8, 24, 16, blk - 64);
    else if (blk < 112)  conv_b_body(Wout,  BswO,  256, 16, 16, 0,  blk - 80);
    else if (blk < 114) {
        const int t = (blk - 112) * 256 + threadIdx.x;
        if (t < 384) fbias[t] = (t < 256) ? boff[t] : battn[t - 256];
        else if (t < 416) {
            const int j = t - 384;
            value[-32 + j] = 0;                            // front pad (64 B)
            value[(size_t)M_TOTAL * 256 + j] = 0;          // back pad (64 B)
        }
    } else {
        // zero the tail rows 26588..26591 of AccSw (rt=1661, m=12..15)
        const int idx = threadIdx.x;
        if (idx < 128) {
            const int kc = idx >> 4;
            const int sub = idx & 15;
            const int lane = (12 + (sub & 3)) + 16 * (sub >> 2);
            const size_t unit = (size_t)(1661 * 8 + kc) * 64 + lane;
            short8 z = (short8){0, 0, 0, 0, 0, 0, 0, 0};
            ((short8*)AccSw)[unit] = z;
        }
    }
}

// ---------------------------------------------------------------------------
// Front GEMM body with LDS-staged A, RT row-tiles (RT*16 rows) per block.
//   Stage: RT*16 x 256 fp32 -> bf16 LDS, coalesced float4 loads, cvt_pk,
//          XOR-swizzle byte ^= (row&7)<<4 for conflict-free ds_read_b128.
// OUTMODE 0: fp32 row-major [M, NT*16].  OUTMODE 1: FP16 head-major value
//   layout value[((b*8+h)*LEN + pos)*32 + d].
// ---------------------------------------------------------------------------
template <int NT, int OUTMODE, int RT>
__device__ __forceinline__ void gemm_lds_full(unsigned short* __restrict__ sA,
                                              const float* __restrict__ A,
                                              const unsigned short* __restrict__ Bsw,
                                              const float* __restrict__ bias,
                                              void* __restrict__ Cout, int M, int rtb) {
    constexpr int NTW = NT / 4;
    constexpr int ROWS = RT * 16;
    const int tid = threadIdx.x;
    const int lane = tid & 63;
    const int wave = tid >> 6;
    const int trow = rtb * ROWS;

    // ---- stage A tile (coalesced, bf16, swizzled) ----
#pragma unroll
    for (int i = 0; i < RT * 4; ++i) {
        const int li = i * 1024 + tid * 4;          // float index within tile
        const int lrow = li >> 8;
        const int lcol = li & 255;
        const int srow = min(trow + lrow, M - 1);
        const float4 f = *(const float4*)(A + (size_t)srow * 256 + lcol);
        uint2 pk;
        pk.x = cvtpk_bf16(f.x, f.y);
        pk.y = cvtpk_bf16(f.z, f.w);
        const int lb = (li * 2) ^ ((lrow & 7) << 4);
        *(uint2*)((char*)sA + lb) = pk;
    }
    __syncthreads();

    const int m = lane & 15;
    const int q = lane >> 4;
    const short8* Bu = (const short8*)Bsw;

    floatx4 acc[RT][NTW];
#pragma unroll
    for (int r = 0; r < RT; ++r)
#pragma unroll
        for (int t = 0; t < NTW; ++t) acc[r][t] = (floatx4){0.f, 0.f, 0.f, 0.f};

    const int swz = (m & 7) << 4;
#pragma unroll 2
    for (int kc = 0; kc < 8; ++kc) {
        short8 a[RT];
#pragma unroll
        for (int r = 0; r < RT; ++r) {
            const int fb = ((m + r * 16) * 512 + kc * 64 + q * 16) ^ swz;
            a[r] = *(const short8*)((const char*)sA + fb);
        }
#pragma unroll
        for (int t = 0; t < NTW; ++t) {
            const short8 b = Bu[(size_t)(kc * NT + wave * NTW + t) * 64 + lane];
#pragma unroll
            for (int r = 0; r < RT; ++r)
                acc[r][t] = __builtin_amdgcn_mfma_f32_16x16x32_bf16(a[r], b, acc[r][t], 0, 0, 0);
        }
    }

    const int N = NT * 16;
    const int colq = lane & 15;
    const int rowq = (lane >> 4) * 4;
#pragma unroll
    for (int t = 0; t < NTW; ++t) {
        const int col = (wave * NTW + t) * 16 + colq;
        const float bc = bias[col];
#pragma unroll
        for (int r = 0; r < RT; ++r) {
#pragma unroll
            for (int reg = 0; reg < 4; ++reg) {
                const int row = trow + r * 16 + rowq + reg;
                if (row < M) {
                    const float v = acc[r][t][reg] + bc;
                    if (OUTMODE == 1) {
                        const int bb = row >= LEN_IN_C;
                        const int pos = row - (bb ? LEN_IN_C : 0);
                        const int hh = col >> 5;
                        const int dd = col & 31;
                        ((unsigned short*)Cout)[((size_t)((bb << 3) + hh) * LEN_IN_C + pos) * 32 + dd] = f2h(v);
                    } else {
                        ((float*)Cout)[(size_t)row * N + col] = v;
                    }
                }
            }
        }
    }
}

// Combined front GEMM: even blocks -> value projection, odd -> off/attn GEMM.
// 32-row tiles both: 1662 blocks, 16 KB LDS -> high occupancy (round-3 proven).
__global__ __launch_bounds__(256) void front_gemm_kernel(const float* __restrict__ inflat,
                                                         const float* __restrict__ query,
                                                         const unsigned short* __restrict__ BswV,
                                                         const unsigned short* __restrict__ BswOA,
                                                         const float* __restrict__ bv,
                                                         const float* __restrict__ fbias,
                                                         unsigned short* __restrict__ value,
                                                         float* __restrict__ fused, int M) {
    __shared__ unsigned short sA[32 * 256];       // 16 KB
    const int x = blockIdx.x;
    const int rt32 = x >> 1;
    if ((x & 1) == 0)
        gemm_lds_full<16, 1, 2>(sA, inflat, BswV, bv, (void*)value, M, rt32);
    else
        gemm_lds_full<24, 0, 2>(sA, query, BswOA, fbias, (void*)fused, M, rt32);
}

// ---------------------------------------------------------------------------
// Back GEMM: pre-swizzled bf16 A (sampler output), one 16-row tile per block
// (1662 blocks, max TLP).
// ---------------------------------------------------------------------------
__global__ __launch_bounds__(256) void back_gemm_kernel(const unsigned short* __restrict__ Asw,
                                                        const unsigned short* __restrict__ Bsw,
                                                        const float* __restrict__ bias,
                                                        float* __restrict__ Cout, int M) {
    constexpr int NT = 16;
    constexpr int NTW = 4;
    const int tid = threadIdx.x;
    const int lane = tid & 63;
    const int wave = tid >> 6;
    const int rt = blockIdx.x;

    const short8* Au = (const short8*)Asw;
    const short8* Bu = (const short8*)Bsw;

    floatx4 acc[NTW];
#pragma unroll
    for (int t = 0; t < NTW; ++t) acc[t] = (floatx4){0.f, 0.f, 0.f, 0.f};

#pragma unroll 2
    for (int kc = 0; kc < 8; ++kc) {
        const short8 a = Au[(size_t)(rt * 8 + kc) * 64 + lane];
#pragma unroll
        for (int t = 0; t < NTW; ++t) {
            const short8 b = Bu[(size_t)(kc * NT + wave * NTW + t) * 64 + lane];
            acc[t] = __builtin_amdgcn_mfma_f32_16x16x32_bf16(a, b, acc[t], 0, 0, 0);
        }
    }

    const int colq = lane & 15;
    const int rowq = (lane >> 4) * 4;
#pragma unroll
    for (int t = 0; t < NTW; ++t) {
        const int col = (wave * NTW + t) * 16 + colq;
        const float bc = bias[col];
#pragma unroll
        for (int reg = 0; reg < 4; ++reg) {
            const int row = rt * 16 + rowq + reg;
            if (row < M)
                Cout[(size_t)row * 256 + col] = acc[t][reg] + bc;
        }
    }
}

// ---------------------------------------------------------------------------
// Sampler v7: head-per-XCD + FP16 value + v_fma_mix_f32 + fused 16-B LDS
// point-descriptor {offTop, offBot, wTop, wBot} per (slot, side):
//   ONE ds_read_b128 per point (was 2x b64), bank-quad map (qq+pt)%8 is
//   uniform -> ~0 conflicts.
// ---------------------------------------------------------------------------
__global__ __launch_bounds__(256, 8) void msda_sample_kernel(const float* __restrict__ refp,
                                                             const unsigned short* __restrict__ value,
                                                             const float* __restrict__ fused,
                                                             unsigned short* __restrict__ AccSw) {
    constexpr int lvl_hw[4] = {100, 50, 25, 13};
    constexpr int lvl_s[4] = {0, 10000, 12500, 13125};

    const int wg = blockIdx.x;
    const int h = wg & 7;
    const int q0 = (wg >> 3) * GQ;
    const int tid = threadIdx.x;

    __shared__ float s_ref[GQ * 8];
    __shared__ uint4 s_pd[2][GQ * 17];

    s_ref[tid] = refp[min(q0 * 8 + tid, M_TOTAL * 8 - 1)];
    __syncthreads();

#pragma unroll
    for (int jj = 0; jj < 2; ++jj) {
        const int job = jj * 256 + tid;          // 0..511
        const int qq = job >> 4;                 // 0..31
        const int t16 = job & 15;                // l*4+p
        const int l = t16 >> 2;
        const int bq = min(q0 + qq, M_TOTAL - 1);
        const int b = (bq >= LQ_C) ? 1 : 0;

        // softmax over the 16 (l,p) logits of head h (16 consecutive lanes)
        const float logit = fused[(size_t)bq * 384 + 256 + h * 16 + t16];
        float m = logit;
#pragma unroll
        for (int mask = 1; mask < 16; mask <<= 1) m = fmaxf(m, __shfl_xor(m, mask));
        const float e = expf(logit - m);
        float s = e;
#pragma unroll
        for (int mask = 1; mask < 16; mask <<= 1) s += __shfl_xor(s, mask);
        const float aw = e / s;

        const int whl = lvl_hw[l];
        const float fwh = (float)whl;
        const float2 oxy = *(const float2*)(fused + (size_t)bq * 384 + (h * 16 + t16) * 2);
        const float x = s_ref[qq * 8 + l * 2] * fwh + oxy.x - 0.5f;
        const float y = s_ref[qq * 8 + l * 2 + 1] * fwh + oxy.y - 0.5f;
        const float x0f = floorf(x), y0f = floorf(y);
        const float tx = x - x0f, ty = y - y0f;
        const int ix0 = (int)x0f, iy0 = (int)y0f;

        const bool xv0 = (unsigned)ix0 < (unsigned)whl;
        const bool xv1 = (unsigned)(ix0 + 1) < (unsigned)whl;
        const bool yv0 = (unsigned)iy0 < (unsigned)whl;
        const bool yv1 = (unsigned)(iy0 + 1) < (unsigned)whl;

        // pair base x: clamp to [-1, w-1]; invalid halves carry zero weight
        const int cxp = min(max(ix0, -1), whl - 1);
        const int cy0 = min(max(iy0, 0), whl - 1);
        const int cy1 = min(max(iy0 + 1, 0), whl - 1);

        const int posb = (b * 8 + h) * LEN_IN_C + lvl_s[l];
        const int offT = (posb + cy0 * whl + cxp) * 64;   // BYTE offsets, 128-B pairs
        const int offB = (posb + cy1 * whl + cxp) * 64;
        const float w00 = (xv0 && yv0) ? aw * (1.f - tx) * (1.f - ty) : 0.f;
        const float w01 = (xv1 && yv0) ? aw * tx * (1.f - ty) : 0.f;
        const float w10 = (xv0 && yv1) ? aw * (1.f - tx) * ty : 0.f;
        const float w11 = (xv1 && yv1) ? aw * tx * ty : 0.f;
        const int slot = qq * 17 + t16;
        uint4 d0, d1;
        d0.x = (unsigned)offT; d0.y = (unsigned)offB;
        d0.z = __float_as_uint(w00); d0.w = __float_as_uint(w10);   // left corner
        d1.x = (unsigned)offT; d1.y = (unsigned)offB;
        d1.z = __float_as_uint(w01); d1.w = __float_as_uint(w11);   // right corner
        s_pd[0][slot] = d0;
        s_pd[1][slot] = d1;
    }
    __syncthreads();

    const int qq = tid >> 3;
    const int l8 = tid & 7;
    const char* vbp = (const char*)value + l8 * 16;
    const int pbase = qq * 17;
    const int side = (l8 >> 2) & 1;

    float a0 = 0.f, a1 = 0.f, a2 = 0.f, a3 = 0.f;
    float a4 = 0.f, a5 = 0.f, a6 = 0.f, a7 = 0.f;
#pragma unroll 2
    for (int pt = 0; pt < 16; ++pt) {
        const uint4 d = s_pd[side][pbase + pt];
        const float wt = __uint_as_float(d.z);
        const float wb = __uint_as_float(d.w);
        const uint4 vt = *(const uint4*)(vbp + (int)d.x);
        const uint4 vb = *(const uint4*)(vbp + (int)d.y);
        FMAMIX_LO(a0, vt.x, wt); FMAMIX_HI(a1, vt.x, wt);
        FMAMIX_LO(a2, vt.y, wt); FMAMIX_HI(a3, vt.y, wt);
        FMAMIX_LO(a4, vt.z, wt); FMAMIX_HI(a5, vt.z, wt);
        FMAMIX_LO(a6, vt.w, wt); FMAMIX_HI(a7, vt.w, wt);
        FMAMIX_LO(a0, vb.x, wb); FMAMIX_HI(a1, vb.x, wb);
        FMAMIX_LO(a2, vb.y, wb); FMAMIX_HI(a3, vb.y, wb);
        FMAMIX_LO(a4, vb.z, wb); FMAMIX_HI(a5, vb.z, wb);
        FMAMIX_LO(a6, vb.w, wb); FMAMIX_HI(a7, vb.w, wb);
    }

    a0 += __shfl_xor(a0, 4); a1 += __shfl_xor(a1, 4);
    a2 += __shfl_xor(a2, 4); a3 += __shfl_xor(a3, 4);
    a4 += __shfl_xor(a4, 4); a5 += __shfl_xor(a5, 4);
    a6 += __shfl_xor(a6, 4); a7 += __shfl_xor(a7, 4);

    const int bq = q0 + qq;
    if (side == 0 && bq < M_TOTAL) {
        // write swizzled A-fragment: row = bq, col = h*32 + (l8&3)*8 (+0..7)
        const int rt = bq >> 4, mm = bq & 15;
        const int unit = (rt * 8 + h) * 64 + ((l8 & 3) * 16 + mm);
        uint4 o;
        o.x = cvtpk_bf16(a0, a1);
        o.y = cvtpk_bf16(a2, a3);
        o.z = cvtpk_bf16(a4, a5);
        o.w = cvtpk_bf16(a6, a7);
        *(uint4*)(AccSw + (size_t)unit * 8) = o;
    }
}

extern "C" void kernel_launch(void* const* d_in, const int* in_sizes, int n_in,
                              void* d_out, int out_size, void* d_ws, size_t ws_size,
                              hipStream_t stream) {
    const float* query  = (const float*)d_in[0];
    const float* refp   = (const float*)d_in[1];
    const float* inflat = (const float*)d_in[2];
    const float* Wv    = (const float*)d_in[4];
    const float* bv    = (const float*)d_in[5];
    const float* Woff  = (const float*)d_in[6];
    const float* boff  = (const float*)d_in[7];
    const float* Wattn = (const float*)d_in[8];
    const float* battn = (const float*)d_in[9];
    const float* Wout  = (const float*)d_in[10];
    const float* bout  = (const float*)d_in[11];
    float* out = (float*)d_out;

    char* p = (char*)d_ws;
    unsigned short* AccSw = (unsigned short*)p;
    p += (size_t)MT_TILES * 8 * 64 * 8 * sizeof(unsigned short);          // 13.6 MB
    unsigned short* BswV = (unsigned short*)p;   p += (size_t)8 * 16 * 64 * 8 * 2;
    unsigned short* BswOA = (unsigned short*)p;  p += (size_t)8 * 24 * 64 * 8 * 2;
    unsigned short* BswO = (unsigned short*)p;   p += (size_t)8 * 16 * 64 * 8 * 2;
    float* fbias = (float*)p;                    p += 384 * sizeof(float);
    unsigned short* value = (unsigned short*)p + 32;                      // 64 B front pad
    p += ((size_t)M_TOTAL * 256 + 64) * sizeof(unsigned short);           // + 64 B back pad
    float* fused = (float*)p;                    p += (size_t)M_TOTAL * 384 * 4;

    const int M = M_TOTAL;

    conv_weights_kernel<<<115, 256, 0, stream>>>(Wv, Woff, Wattn, Wout, boff, battn,
                                                 BswV, BswOA, BswO, fbias, value, AccSw);
    front_gemm_kernel<<<RT32_TILES * 2, 256, 0, stream>>>(inflat, query, BswV, BswOA,
                                                          bv, fbias, value, fused, M);
    msda_sample_kernel<<<QBLKS * 8, 256, 0, stream>>>(refp, value, fused, AccSw);
    back_gemm_kernel<<<MT_TILES, 256, 0, stream>>>(AccSw, BswO, bout, out, M);
}

// Round 6
// 198.308 us; speedup vs baseline: 1.0143x; 1.0143x over previous
//
#include <hip/hip_runtime.h>

#define NH 8
#define HD 32
#define NL 4
#define NP 4
#define DM 256
#define LEN_IN_C 13294
#define LQ_C 13294
#define B_C 2
#define M_TOTAL (B_C * LQ_C)           // 26588
#define MT_TILES 1662                  // ceil(26588/16)
#define RT32_TILES 831                 // ceil(26588/32)
#define GQ 32                          // queries per sampler block
#define QBLKS 831                      // ceil(26588/32)

typedef __attribute__((ext_vector_type(8))) short short8;
typedef __attribute__((ext_vector_type(4))) float floatx4;

__device__ __forceinline__ unsigned short f2bf(float x) {
    union { float f; unsigned int u; } a; a.f = x;
    unsigned int r = (a.u + 0x7FFFu + ((a.u >> 16) & 1u)) >> 16;
    return (unsigned short)r;
}
__device__ __forceinline__ unsigned short f2h(float x) {
    unsigned int r;
    asm("v_cvt_f16_f32 %0, %1" : "=v"(r) : "v"(x));
    return (unsigned short)r;
}
__device__ __forceinline__ unsigned int cvtpk_bf16(float lo, float hi) {
    unsigned int r;
    asm("v_cvt_pk_bf16_f32 %0, %1, %2" : "=v"(r) : "v"(lo), "v"(hi));
    return r;
}

// acc += f16(lo/hi half of v) * w   — one VALU op, f32 accumulate.
#define FMAMIX_LO(acc, v, w) \
    asm("v_fma_mix_f32 %0, %1, %2, %0 op_sel_hi:[1,0,0]" : "+v"(acc) : "v"(v), "v"(w))
#define FMAMIX_HI(acc, v, w) \
    asm("v_fma_mix_f32 %0, %1, %2, %0 op_sel:[1,0,0] op_sel_hi:[1,0,0]" : "+v"(acc) : "v"(v), "v"(w))

// ---------------------------------------------------------------------------
// Weight conversions + bias fuse + pad/tail zeroing in ONE kernel.
// ---------------------------------------------------------------------------
__device__ __forceinline__ void conv_b_body(const float* __restrict__ W,
                                            unsigned short* __restrict__ Bsw,
                                            int Nsrc, int NTsrc, int NTtotal, int ntOff,
                                            int vblk) {
    const int u = vblk * 256 + threadIdx.x;
    const int lane = u & 63;
    const int unit = u >> 6;
    const int ntl = unit % NTsrc;
    const int kc = unit / NTsrc;
    const int n = ntl * 16 + (lane & 15);
    const int k0 = kc * 32 + (lane >> 4) * 8;
    short8 v;
#pragma unroll
    for (int j = 0; j < 8; ++j)
        v[j] = (short)f2bf(W[(size_t)(k0 + j) * Nsrc + n]);
    ((short8*)Bsw)[(size_t)(kc * NTtotal + ntOff + ntl) * 64 + lane] = v;
}

__global__ __launch_bounds__(256) void conv_weights_kernel(const float* __restrict__ Wv,
                                                           const float* __restrict__ Woff,
                                                           const float* __restrict__ Wattn,
                                                           const float* __restrict__ Wout,
                                                           const float* __restrict__ boff,
                                                           const float* __restrict__ battn,
                                                           unsigned short* __restrict__ BswV,
                                                           unsigned short* __restrict__ BswOA,
                                                           unsigned short* __restrict__ BswO,
                                                           float* __restrict__ fbias,
                                                           unsigned short* __restrict__ value,
                                                           unsigned short* __restrict__ AccSw) {
    const int blk = blockIdx.x;
    if (blk < 32)        conv_b_body(Wv,    BswV,  256, 16, 16, 0,  blk);
    else if (blk < 64)   conv_b_body(Woff,  BswOA, 256, 16, 24, 0,  blk - 32);
    else if (blk < 80)   conv_b_body(Wattn, BswOA, 128,  8, 24, 16, blk - 64);
    else if (blk < 112)  conv_b_body(Wout,  BswO,  256, 16, 16, 0,  blk - 80);
    else if (blk < 114) {
        const int t = (blk - 112) * 256 + threadIdx.x;
        if (t < 384) fbias[t] = (t < 256) ? boff[t] : battn[t - 256];
        else if (t < 416) {
            const int j = t - 384;
            value[-32 + j] = 0;                            // front pad (64 B)
            value[(size_t)M_TOTAL * 256 + j] = 0;          // back pad (64 B)
        }
    } else {
        // zero the tail rows 26588..26591 of AccSw (rt=1661, m=12..15)
        const int idx = threadIdx.x;
        if (idx < 128) {
            const int kc = idx >> 4;
            const int sub = idx & 15;
            const int lane = (12 + (sub & 3)) + 16 * (sub >> 2);
            const size_t unit = (size_t)(1661 * 8 + kc) * 64 + lane;
            short8 z = (short8){0, 0, 0, 0, 0, 0, 0, 0};
            ((short8*)AccSw)[unit] = z;
        }
    }
}

// ---------------------------------------------------------------------------
// Front GEMM, LDS-staged A (32 rows), EXPLICIT register double-buffer:
//   bank nxt loads B-frags + A-frags for kc+1 while bank cur feeds MFMA.
//   Fully-unrolled kc loop -> all bank indices compile-time (no scratch).
// OUTMODE 0: fp32 row-major [M, NT*16].  OUTMODE 1: FP16 head-major value
//   layout value[((b*8+h)*LEN + pos)*32 + d].
// ---------------------------------------------------------------------------
template <int NT, int OUTMODE>
__device__ __forceinline__ void gemm_lds_pipe(unsigned short* __restrict__ sA,
                                              const float* __restrict__ A,
                                              const unsigned short* __restrict__ Bsw,
                                              const float* __restrict__ bias,
                                              void* __restrict__ Cout, int M, int rt32) {
    constexpr int NTW = NT / 4;
    const int tid = threadIdx.x;
    const int lane = tid & 63;
    const int wave = tid >> 6;
    const int trow = rt32 * 32;

    // ---- stage A tile (coalesced, bf16, swizzled) ----
#pragma unroll
    for (int i = 0; i < 8; ++i) {
        const int li = i * 1024 + tid * 4;          // float index within tile
        const int lrow = li >> 8;
        const int lcol = li & 255;
        const int srow = min(trow + lrow, M - 1);
        const float4 f = *(const float4*)(A + (size_t)srow * 256 + lcol);
        uint2 pk;
        pk.x = cvtpk_bf16(f.x, f.y);
        pk.y = cvtpk_bf16(f.z, f.w);
        const int lb = (li * 2) ^ ((lrow & 7) << 4);
        *(uint2*)((char*)sA + lb) = pk;
    }
    __syncthreads();

    const int m = lane & 15;
    const int q = lane >> 4;
    const short8* Bu = (const short8*)Bsw;
    const int swz = (m & 7) << 4;

    floatx4 acc[2][NTW];
#pragma unroll
    for (int r = 0; r < 2; ++r)
#pragma unroll
        for (int t = 0; t < NTW; ++t) acc[r][t] = (floatx4){0.f, 0.f, 0.f, 0.f};

    short8 br[2][NTW];
    short8 ar[2][2];
#pragma unroll
    for (int t = 0; t < NTW; ++t)
        br[0][t] = Bu[(size_t)(0 * NT + wave * NTW + t) * 64 + lane];
    ar[0][0] = *(const short8*)((const char*)sA + ((m * 512 + 0 * 64 + q * 16) ^ swz));
    ar[0][1] = *(const short8*)((const char*)sA + (((m + 16) * 512 + 0 * 64 + q * 16) ^ swz));

#pragma unroll
    for (int kc = 0; kc < 8; ++kc) {
        const int cur = kc & 1;
        const int nxt = cur ^ 1;
        if (kc < 7) {
#pragma unroll
            for (int t = 0; t < NTW; ++t)
                br[nxt][t] = Bu[(size_t)((kc + 1) * NT + wave * NTW + t) * 64 + lane];
            ar[nxt][0] = *(const short8*)((const char*)sA + ((m * 512 + (kc + 1) * 64 + q * 16) ^ swz));
            ar[nxt][1] = *(const short8*)((const char*)sA + (((m + 16) * 512 + (kc + 1) * 64 + q * 16) ^ swz));
        }
#pragma unroll
        for (int t = 0; t < NTW; ++t) {
            acc[0][t] = __builtin_amdgcn_mfma_f32_16x16x32_bf16(ar[cur][0], br[cur][t], acc[0][t], 0, 0, 0);
            acc[1][t] = __builtin_amdgcn_mfma_f32_16x16x32_bf16(ar[cur][1], br[cur][t], acc[1][t], 0, 0, 0);
        }
    }

    const int N = NT * 16;
    const int colq = lane & 15;
    const int rowq = (lane >> 4) * 4;
#pragma unroll
    for (int t = 0; t < NTW; ++t) {
        const int col = (wave * NTW + t) * 16 + colq;
        const float bc = bias[col];
#pragma unroll
        for (int r = 0; r < 2; ++r) {
#pragma unroll
            for (int reg = 0; reg < 4; ++reg) {
                const int row = trow + r * 16 + rowq + reg;
                if (row < M) {
                    const float v = acc[r][t][reg] + bc;
                    if (OUTMODE == 1) {
                        const int bb = row >= LEN_IN_C;
                        const int pos = row - (bb ? LEN_IN_C : 0);
                        const int hh = col >> 5;
                        const int dd = col & 31;
                        ((unsigned short*)Cout)[((size_t)((bb << 3) + hh) * LEN_IN_C + pos) * 32 + dd] = f2h(v);
                    } else {
                        ((float*)Cout)[(size_t)row * N + col] = v;
                    }
                }
            }
        }
    }
}

// Combined front GEMM: even blocks -> value projection, odd -> off/attn GEMM.
__global__ __launch_bounds__(256) void front_gemm_kernel(const float* __restrict__ inflat,
                                                         const float* __restrict__ query,
                                                         const unsigned short* __restrict__ BswV,
                                                         const unsigned short* __restrict__ BswOA,
                                                         const float* __restrict__ bv,
                                                         const float* __restrict__ fbias,
                                                         unsigned short* __restrict__ value,
                                                         float* __restrict__ fused, int M) {
    __shared__ unsigned short sA[32 * 256];       // 16 KB
    const int x = blockIdx.x;
    const int rt32 = x >> 1;
    if ((x & 1) == 0)
        gemm_lds_pipe<16, 1>(sA, inflat, BswV, bv, (void*)value, M, rt32);
    else
        gemm_lds_pipe<24, 0>(sA, query, BswOA, fbias, (void*)fused, M, rt32);
}

// ---------------------------------------------------------------------------
// Back GEMM: pre-swizzled bf16 A (sampler output), two 16-row tiles per block,
// explicit A+B register double-buffer (same pipelining as front).
// ---------------------------------------------------------------------------
__global__ __launch_bounds__(256) void back_gemm_kernel(const unsigned short* __restrict__ Asw,
                                                        const unsigned short* __restrict__ Bsw,
                                                        const float* __restrict__ bias,
                                                        float* __restrict__ Cout, int M) {
    constexpr int NT = 16;
    constexpr int NTW = 4;
    const int tid = threadIdx.x;
    const int lane = tid & 63;
    const int wave = tid >> 6;
    const int rt0 = blockIdx.x * 2;

    const short8* Au = (const short8*)Asw;
    const short8* Bu = (const short8*)Bsw;

    floatx4 acc[2][NTW];
#pragma unroll
    for (int r = 0; r < 2; ++r)
#pragma unroll
        for (int t = 0; t < NTW; ++t) acc[r][t] = (floatx4){0.f, 0.f, 0.f, 0.f};

    short8 br[2][NTW];
    short8 ar[2][2];
#pragma unroll
    for (int t = 0; t < NTW; ++t)
        br[0][t] = Bu[(size_t)(0 * NT + wave * NTW + t) * 64 + lane];
    ar[0][0] = Au[(size_t)(rt0 * 8 + 0) * 64 + lane];
    ar[0][1] = Au[(size_t)((rt0 + 1) * 8 + 0) * 64 + lane];

#pragma unroll
    for (int kc = 0; kc < 8; ++kc) {
        const int cur = kc & 1;
        const int nxt = cur ^ 1;
        if (kc < 7) {
#pragma unroll
            for (int t = 0; t < NTW; ++t)
                br[nxt][t] = Bu[(size_t)((kc + 1) * NT + wave * NTW + t) * 64 + lane];
            ar[nxt][0] = Au[(size_t)(rt0 * 8 + kc + 1) * 64 + lane];
            ar[nxt][1] = Au[(size_t)((rt0 + 1) * 8 + kc + 1) * 64 + lane];
        }
#pragma unroll
        for (int t = 0; t < NTW; ++t) {
            acc[0][t] = __builtin_amdgcn_mfma_f32_16x16x32_bf16(ar[cur][0], br[cur][t], acc[0][t], 0, 0, 0);
            acc[1][t] = __builtin_amdgcn_mfma_f32_16x16x32_bf16(ar[cur][1], br[cur][t], acc[1][t], 0, 0, 0);
        }
    }

    const int colq = lane & 15;
    const int rowq = (lane >> 4) * 4;
#pragma unroll
    for (int t = 0; t < NTW; ++t) {
        const int col = (wave * NTW + t) * 16 + colq;
        const float bc = bias[col];
#pragma unroll
        for (int r = 0; r < 2; ++r) {
#pragma unroll
            for (int reg = 0; reg < 4; ++reg) {
                const int row = (rt0 + r) * 16 + rowq + reg;
                if (row < M)
                    Cout[(size_t)row * 256 + col] = acc[r][t][reg] + bc;
            }
        }
    }
}

// ---------------------------------------------------------------------------
// Sampler v8: head-per-XCD + FP16 value + v_fma_mix_f32, 4-point chunked
// DOUBLE-BUFFERED gather pipeline: bank nxt issues 4 descriptor ds_reads +
// 8 value gathers for chunk c+1 while bank cur's 64 fma_mix run -> 8 loads
// in flight per wave (was ~2). launch_bounds (256,4): VGPR cap 128.
// ---------------------------------------------------------------------------
__global__ __launch_bounds__(256, 4) void msda_sample_kernel(const float* __restrict__ refp,
                                                             const unsigned short* __restrict__ value,
                                                             const float* __restrict__ fused,
                                                             unsigned short* __restrict__ AccSw) {
    constexpr int lvl_hw[4] = {100, 50, 25, 13};
    constexpr int lvl_s[4] = {0, 10000, 12500, 13125};

    const int wg = blockIdx.x;
    const int h = wg & 7;
    const int q0 = (wg >> 3) * GQ;
    const int tid = threadIdx.x;

    __shared__ float s_ref[GQ * 8];
    __shared__ uint4 s_pd[2][GQ * 17];

    s_ref[tid] = refp[min(q0 * 8 + tid, M_TOTAL * 8 - 1)];
    __syncthreads();

#pragma unroll
    for (int jj = 0; jj < 2; ++jj) {
        const int job = jj * 256 + tid;          // 0..511
        const int qq = job >> 4;                 // 0..31
        const int t16 = job & 15;                // l*4+p
        const int l = t16 >> 2;
        const int bq = min(q0 + qq, M_TOTAL - 1);
        const int b = (bq >= LQ_C) ? 1 : 0;

        // softmax over the 16 (l,p) logits of head h (16 consecutive lanes)
        const float logit = fused[(size_t)bq * 384 + 256 + h * 16 + t16];
        float m = logit;
#pragma unroll
        for (int mask = 1; mask < 16; mask <<= 1) m = fmaxf(m, __shfl_xor(m, mask));
        const float e = expf(logit - m);
        float s = e;
#pragma unroll
        for (int mask = 1; mask < 16; mask <<= 1) s += __shfl_xor(s, mask);
        const float aw = e / s;

        const int whl = lvl_hw[l];
        const float fwh = (float)whl;
        const float2 oxy = *(const float2*)(fused + (size_t)bq * 384 + (h * 16 + t16) * 2);
        const float x = s_ref[qq * 8 + l * 2] * fwh + oxy.x - 0.5f;
        const float y = s_ref[qq * 8 + l * 2 + 1] * fwh + oxy.y - 0.5f;
        const float x0f = floorf(x), y0f = floorf(y);
        const float tx = x - x0f, ty = y - y0f;
        const int ix0 = (int)x0f, iy0 = (int)y0f;

        const bool xv0 = (unsigned)ix0 < (unsigned)whl;
        const bool xv1 = (unsigned)(ix0 + 1) < (unsigned)whl;
        const bool yv0 = (unsigned)iy0 < (unsigned)whl;
        const bool yv1 = (unsigned)(iy0 + 1) < (unsigned)whl;

        // pair base x: clamp to [-1, w-1]; invalid halves carry zero weight
        const int cxp = min(max(ix0, -1), whl - 1);
        const int cy0 = min(max(iy0, 0), whl - 1);
        const int cy1 = min(max(iy0 + 1, 0), whl - 1);

        const int posb = (b * 8 + h) * LEN_IN_C + lvl_s[l];
        const int offT = (posb + cy0 * whl + cxp) * 64;   // BYTE offsets, 128-B pairs
        const int offB = (posb + cy1 * whl + cxp) * 64;
        const float w00 = (xv0 && yv0) ? aw * (1.f - tx) * (1.f - ty) : 0.f;
        const float w01 = (xv1 && yv0) ? aw * tx * (1.f - ty) : 0.f;
        const float w10 = (xv0 && yv1) ? aw * (1.f - tx) * ty : 0.f;
        const float w11 = (xv1 && yv1) ? aw * tx * ty : 0.f;
        const int slot = qq * 17 + t16;
        uint4 d0, d1;
        d0.x = (unsigned)offT; d0.y = (unsigned)offB;
        d0.z = __float_as_uint(w00); d0.w = __float_as_uint(w10);   // left corner
        d1.x = (unsigned)offT; d1.y = (unsigned)offB;
        d1.z = __float_as_uint(w01); d1.w = __float_as_uint(w11);   // right corner
        s_pd[0][slot] = d0;
        s_pd[1][slot] = d1;
    }
    __syncthreads();

    const int qq = tid >> 3;
    const int l8 = tid & 7;
    const char* vbp = (const char*)value + l8 * 16;
    const int side = (l8 >> 2) & 1;
    const uint4* pd = &s_pd[side][qq * 17];

    uint4 dsc[2][4];
    uint4 vt[2][4], vb[2][4];
#pragma unroll
    for (int j = 0; j < 4; ++j) dsc[0][j] = pd[j];
#pragma unroll
    for (int j = 0; j < 4; ++j) {
        vt[0][j] = *(const uint4*)(vbp + (int)dsc[0][j].x);
        vb[0][j] = *(const uint4*)(vbp + (int)dsc[0][j].y);
    }

    float a0 = 0.f, a1 = 0.f, a2 = 0.f, a3 = 0.f;
    float a4 = 0.f, a5 = 0.f, a6 = 0.f, a7 = 0.f;
#pragma unroll
    for (int c = 0; c < 4; ++c) {
        const int cur = c & 1;
        const int nxt = cur ^ 1;
        if (c < 3) {
#pragma unroll
            for (int j = 0; j < 4; ++j) dsc[nxt][j] = pd[(c + 1) * 4 + j];
#pragma unroll
            for (int j = 0; j < 4; ++j) {
                vt[nxt][j] = *(const uint4*)(vbp + (int)dsc[nxt][j].x);
                vb[nxt][j] = *(const uint4*)(vbp + (int)dsc[nxt][j].y);
            }
        }
#pragma unroll
        for (int j = 0; j < 4; ++j) {
            const float wt = __uint_as_float(dsc[cur][j].z);
            const float wb = __uint_as_float(dsc[cur][j].w);
            const uint4 t4 = vt[cur][j];
            const uint4 b4 = vb[cur][j];
            FMAMIX_LO(a0, t4.x, wt); FMAMIX_HI(a1, t4.x, wt);
            FMAMIX_LO(a2, t4.y, wt); FMAMIX_HI(a3, t4.y, wt);
            FMAMIX_LO(a4, t4.z, wt); FMAMIX_HI(a5, t4.z, wt);
            FMAMIX_LO(a6, t4.w, wt); FMAMIX_HI(a7, t4.w, wt);
            FMAMIX_LO(a0, b4.x, wb); FMAMIX_HI(a1, b4.x, wb);
            FMAMIX_LO(a2, b4.y, wb); FMAMIX_HI(a3, b4.y, wb);
            FMAMIX_LO(a4, b4.z, wb); FMAMIX_HI(a5, b4.z, wb);
            FMAMIX_LO(a6, b4.w, wb); FMAMIX_HI(a7, b4.w, wb);
        }
    }

    a0 += __shfl_xor(a0, 4); a1 += __shfl_xor(a1, 4);
    a2 += __shfl_xor(a2, 4); a3 += __shfl_xor(a3, 4);
    a4 += __shfl_xor(a4, 4); a5 += __shfl_xor(a5, 4);
    a6 += __shfl_xor(a6, 4); a7 += __shfl_xor(a7, 4);

    const int bq = q0 + qq;
    if (side == 0 && bq < M_TOTAL) {
        // write swizzled A-fragment: row = bq, col = h*32 + (l8&3)*8 (+0..7)
        const int rt = bq >> 4, mm = bq & 15;
        const int unit = (rt * 8 + h) * 64 + ((l8 & 3) * 16 + mm);
        uint4 o;
        o.x = cvtpk_bf16(a0, a1);
        o.y = cvtpk_bf16(a2, a3);
        o.z = cvtpk_bf16(a4, a5);
        o.w = cvtpk_bf16(a6, a7);
        *(uint4*)(AccSw + (size_t)unit * 8) = o;
    }
}

extern "C" void kernel_launch(void* const* d_in, const int* in_sizes, int n_in,
                              void* d_out, int out_size, void* d_ws, size_t ws_size,
                              hipStream_t stream) {
    const float* query  = (const float*)d_in[0];
    const float* refp   = (const float*)d_in[1];
    const float* inflat = (const float*)d_in[2];
    const float* Wv    = (const float*)d_in[4];
    const float* bv    = (const float*)d_in[5];
    const float* Woff  = (const float*)d_in[6];
    const float* boff  = (const float*)d_in[7];
    const float* Wattn = (const float*)d_in[8];
    const float* battn = (const float*)d_in[9];
    const float* Wout  = (const float*)d_in[10];
    const float* bout  = (const float*)d_in[11];
    float* out = (float*)d_out;

    char* p = (char*)d_ws;
    unsigned short* AccSw = (unsigned short*)p;
    p += (size_t)MT_TILES * 8 * 64 * 8 * sizeof(unsigned short);          // 13.6 MB
    unsigned short* BswV = (unsigned short*)p;   p += (size_t)8 * 16 * 64 * 8 * 2;
    unsigned short* BswOA = (unsigned short*)p;  p += (size_t)8 * 24 * 64 * 8 * 2;
    unsigned short* BswO = (unsigned short*)p;   p += (size_t)8 * 16 * 64 * 8 * 2;
    float* fbias = (float*)p;                    p += 384 * sizeof(float);
    unsigned short* value = (unsigned short*)p + 32;                      // 64 B front pad
    p += ((size_t)M_TOTAL * 256 + 64) * sizeof(unsigned short);           // + 64 B back pad
    float* fused = (float*)p;                    p += (size_t)M_TOTAL * 384 * 4;

    const int M = M_TOTAL;

    conv_weights_kernel<<<115, 256, 0, stream>>>(Wv, Woff, Wattn, Wout, boff, battn,
                                                 BswV, BswOA, BswO, fbias, value, AccSw);
    front_gemm_kernel<<<RT32_TILES * 2, 256, 0, stream>>>(inflat, query, BswV, BswOA,
                                                          bv, fbias, value, fused, M);
    msda_sample_kernel<<<QBLKS * 8, 256, 0, stream>>>(refp, value, fused, AccSw);
    back_gemm_kernel<<<RT32_TILES, 256, 0, stream>>>(AccSw, BswO, bout, out, M);
}